// Round 21
// baseline (10035.889 us; speedup 1.0000x reference)
//
#include <hip/hip_runtime.h>
#include <math.h>

#pragma clang fp contract(off)

// LTC network: B=32, T=128, IN=128, H=256, OUT=128, 5 RK4 steps/t, dt=0.01
// Round 21: bit-exact arithmetic (absmax 0.0 since R9). Lever vs R13 (best,
// 5551us): h-distribution moved to the VMEM pipe. h lives in global (L2);
// uniform-address float4 VECTOR loads (address laundered through an opaque
// VGPR offset so the compiler cannot scalarize to s_load/K$) cost ~4cy TA
// issue and ZERO VALU slots — vs readlane's ~5-6cy/op on the VALU pipe
// (back-solved from R13 counters; R20's batching null killed the hazard
// theory). Coherence: same-CU write-through L1 with write-invalidate +
// __syncthreads (drains vmcnt(0), orders global within block).
// Structure: 512 thr role-split (2 waves/SIMD), w[192] pinned (arch+AGPR),
// rows 192..255 in LDS bundles, partA exchange, 2 barriers/stage.
// Numerics (DO NOT TOUCH — bit-exact vs XLA-CPU golden):
//  dots: ascending-k __builtin_fmaf chain from 0.0; x/bias added after,
//  unfused; sigmoid = 1/(1+CephesExp(-z)) per GenerateVF32Exp; unfused RK4
//  elementwise; fp contract off file-wide.

#define Bn 32
#define Tn 128
#define INn 128
#define Hn 256
#define OUTn 128
#define NSTEPS 5

__device__ __forceinline__ float f32clip(float x, float lo, float hi) {
  float y = (x >= lo) ? x : lo;
  y = (y <= hi) ? y : hi;
  return (x == x) ? y : x;    // NaN propagates (safety; none occur)
}

// XLA CPU GenerateVF32Exp (Cephes expf), bit-exact reconstruction.
__device__ __forceinline__ float xla_expf(float x) {
  x = fminf(x, 88.3762626647950f);         // clamp high
  x = fmaxf(x, -88.3762626647949f);        // clamp low
  float fx = floorf(__builtin_fmaf(x, 1.44269504088896341f, 0.5f)); // fused
  float tmp = __fmul_rn(0.693359375f, fx);         // unfused Cody-Waite hi
  float z  = __fmul_rn(-2.12194440e-4f, fx);       // unfused Cody-Waite lo
  float r  = __fsub_rn(x, tmp);
  r = __fsub_rn(r, z);
  float r2 = __fmul_rn(r, r);
  float y = __builtin_fmaf(r, 1.9875691500e-4f, 1.3981999507e-3f);  // MulAdd
  y = __builtin_fmaf(y, r, 8.3334519073e-3f);
  y = __builtin_fmaf(y, r, 4.1665795894e-2f);
  y = __builtin_fmaf(y, r, 1.6666665459e-1f);
  y = __builtin_fmaf(y, r, 5.0000001201e-1f);
  y = __builtin_fmaf(y, r2, r);
  y = __fadd_rn(1.0f, y);
  int m = (int)fx;                          // FPToSI (fx integral)
  float s = __int_as_float((m + 127) << 23);
  return __fmul_rn(y, s);
}

// LogisticExpander: 1 / (1 + exp(-z))
__device__ __forceinline__ float xla_sigmoid(float zin) {
  float e = xla_expf(-zin);
  return 1.0f / __fadd_rn(1.0f, e);        // IEEE f32 div
}

__global__ __launch_bounds__(256) void k_prep(const float* __restrict__ W_in,
                                              const float* __restrict__ W_out,
                                              const float* __restrict__ W_rec,
                                              const float* __restrict__ W_adapt,
                                              float* __restrict__ W_inT,
                                              float* __restrict__ W_outT,
                                              float* __restrict__ W_recT,
                                              float* __restrict__ W_adaptT) {
  int idx = blockIdx.x * 256 + threadIdx.x;     // 768*256 = 196608
  if (idx < 32768) {            // W_in [256][128] -> W_inT[j][h]
    int h = idx >> 7, j = idx & 127;
    W_inT[j * Hn + h] = W_in[idx];
  } else if (idx < 65536) {     // W_out [128][256] -> W_outT[i][o]
    int k = idx - 32768; int o = k >> 8, i = k & 255;
    W_outT[i * OUTn + o] = W_out[k];
  } else if (idx < 131072) {    // W_rec [256][256] -> W_recT[c][r]
    int k = idx - 65536; int r = k >> 8, c = k & 255;
    W_recT[c * Hn + r] = W_rec[k];
  } else {                      // W_adapt -> W_adaptT[c][r]
    int k = idx - 131072; int r = k >> 8, c = k & 255;
    W_adaptT[c * Hn + r] = W_adapt[k];
  }
}

// emb[b,t,h] = (ascending-i fmaf chain, Eigen) x[b,t,:].W_in[h,:], then + b_in
__global__ __launch_bounds__(256) void k_embed(const float* __restrict__ xin,
                                               const float* __restrict__ W_inT,
                                               const float* __restrict__ b_in,
                                               float* __restrict__ emb) {
  __shared__ float xs[INn];
  int bt = blockIdx.x, h = threadIdx.x;
  if (h < INn) xs[h] = xin[bt * INn + h];
  __syncthreads();
  float d = 0.f;
  #pragma unroll
  for (int j = 0; j < INn; ++j)
    d = __builtin_fmaf(xs[j], W_inT[j * Hn + h], d);  // Eigen gebp chain
  emb[bt * Hn + h] = __fadd_rn(d, b_in[h]);           // + b_in separate op
}

// NOTE: h_g deliberately NOT __restrict__ — per-stage loads alias the stores.
__global__ __launch_bounds__(512)
__attribute__((amdgpu_waves_per_eu(2, 2)))
void k_ltc(const float* __restrict__ W_recT,
           const float* __restrict__ W_adaptT,
           const float* __restrict__ tau,
           const float* __restrict__ emb,
           float* h_g,
           float* __restrict__ h_hist) {
  const int b = blockIdx.x;
  const int tid = threadIdx.x;
  const int role = tid >> 8;     // 0: S-chain (W_rec) + elementwise; 1: A-chain
  const int i = tid & 255;

  __shared__ float partA[Hn];                      // 1 KB
  __shared__ __align__(16) float4 wlds[16][512];   // 128 KB: j=192..255 bundles

  const float* WT = role ? W_adaptT : W_recT;
  float w[192];
  #pragma unroll
  for (int m = 0; m < 192; ++m) w[m] = WT[m * Hn + i];   // coalesced one-time
  #pragma unroll
  for (int m = 0; m < 192; ++m) asm volatile("" : "+v"(w[m]));  // pin resident
  #pragma unroll
  for (int r4 = 0; r4 < 16; ++r4) {                // j = 192..255 into LDS
    float4 v;
    v.x = WT[(192 + 4*r4 + 0) * Hn + i];
    v.y = WT[(192 + 4*r4 + 1) * Hn + i];
    v.z = WT[(192 + 4*r4 + 2) * Hn + i];
    v.w = WT[(192 + 4*r4 + 3) * Hn + i];
    wlds[r4][tid] = v;
  }
  const float tau_i = tau[i];
  const float C_DT6 = (float)(0.01 / 6.0);  // f32(DT/6.0), weak-scalar cast
  float h = 0.f, hcur = 0.f, acc = 0.f;
  float* hgw = h_g + b * Hn;                // per-block state region (L2)
  if (role == 0) hgw[i] = 0.f;
  __syncthreads();                          // store drained + visible

  #pragma unroll 1
  for (int t = 0; t < Tn; ++t) {
    const float x = (role == 0) ? emb[(b * Tn + t) * Hn + i] : 0.f;
    #pragma unroll 1
    for (int s = 0; s < NSTEPS; ++s) {
      #pragma unroll 1
      for (int st = 0; st < 4; ++st) {
        // h via VECTOR loads on the VMEM pipe: uniform address laundered
        // through an opaque VGPR offset (prevents s_load scalarization).
        int off = 0;
        asm volatile("" : "+v"(off));       // opaque, refreshed each stage
        const float4* hg4 = reinterpret_cast<const float4*>(
            reinterpret_cast<const char*>(hgw) + off);
        // dot: ascending-j fmaf chain from 0 (Eigen gebp per-element chain).
        float d = 0.f;
        #pragma unroll
        for (int j4 = 0; j4 < 48; ++j4) {           // j = 0..191, w resident
          const float4 hv = hg4[j4];                // global_load_dwordx4
          d = __builtin_fmaf(hv.x, w[4*j4+0], d);
          d = __builtin_fmaf(hv.y, w[4*j4+1], d);
          d = __builtin_fmaf(hv.z, w[4*j4+2], d);
          d = __builtin_fmaf(hv.w, w[4*j4+3], d);
        }
        #pragma unroll
        for (int r4 = 0; r4 < 16; ++r4) {           // j = 192..255, w from LDS
          const float4 hv = hg4[48 + r4];
          const float4 wb = wlds[r4][tid];
          d = __builtin_fmaf(hv.x, wb.x, d);
          d = __builtin_fmaf(hv.y, wb.y, d);
          d = __builtin_fmaf(hv.z, wb.z, d);
          d = __builtin_fmaf(hv.w, wb.w, d);
        }
        if (role == 1) partA[i] = d;
        __syncthreads();                    // dot reads done; partA visible
        if (role == 0) {
          float S = __fadd_rn(x, d);              // S = x + h@W_rec.T
          float z = __fadd_rn(S, partA[i]);       // S + h@W_adapt.T
          float sig = xla_sigmoid(z);             // 1/(1+exp(-z)), Cephes exp
          float tvc = f32clip(__fmul_rn(tau_i, sig), 1e-6f, 1e6f);
          float kk = __fsub_rn(S, hcur) / tvc;    // separate sub, IEEE div
          if (st == 0) {
            acc = kk;
            hcur = __fadd_rn(h, __fmul_rn(0.005f, kk));
          } else if (st == 1) {
            acc = __fadd_rn(acc, __fmul_rn(2.f, kk));
            hcur = __fadd_rn(h, __fmul_rn(0.005f, kk));
          } else if (st == 2) {
            acc = __fadd_rn(acc, __fmul_rn(2.f, kk));
            hcur = __fadd_rn(h, __fmul_rn(0.01f, kk));
          } else {
            acc = __fadd_rn(acc, kk);
            float dl = f32clip(__fmul_rn(acc, C_DT6), -1e6f, 1e6f);
            h = __fadd_rn(h, dl);
            hcur = h;
          }
          hgw[i] = hcur;                    // publish new state (L2)
        }
        __syncthreads();                    // vmcnt drained; visible to loads
      }
    }
    if (role == 0) h_hist[(b * Tn + t) * Hn + i] = h;
  }
}

// out[b,t,o] = (ascending fmaf chain) h.W_out[o,:], then + b_out[o]
__global__ __launch_bounds__(128) void k_out(const float* __restrict__ h_hist,
                                             const float* __restrict__ W_outT,
                                             const float* __restrict__ b_out,
                                             float* __restrict__ outp) {
  __shared__ float hs[Hn];
  int bt = blockIdx.x, o = threadIdx.x;
  hs[o] = h_hist[bt * Hn + o];
  hs[o + 128] = h_hist[bt * Hn + o + 128];
  __syncthreads();
  float d = 0.f;
  #pragma unroll
  for (int j = 0; j < Hn; ++j)
    d = __builtin_fmaf(hs[j], W_outT[j * OUTn + o], d);
  outp[bt * OUTn + o] = __fadd_rn(d, b_out[o]);
}

extern "C" void kernel_launch(void* const* d_in, const int* in_sizes, int n_in,
                              void* d_out, int out_size, void* d_ws, size_t ws_size,
                              hipStream_t stream) {
  const float* x       = (const float*)d_in[0];
  const float* W_in    = (const float*)d_in[1];
  const float* b_in    = (const float*)d_in[2];
  const float* W_rec   = (const float*)d_in[3];
  const float* W_adapt = (const float*)d_in[4];
  const float* W_out   = (const float*)d_in[5];
  const float* b_out   = (const float*)d_in[6];
  const float* tau     = (const float*)d_in[7];
  float* outp = (float*)d_out;
  float* ws = (float*)d_ws;

  float* W_inT   = ws;                 // 32768
  float* W_outT  = ws + 32768;         // 32768
  float* W_recT  = ws + 65536;         // 65536
  float* W_adaptT= ws + 131072;        // 65536
  float* emb     = ws + 196608;        // 1048576
  float* h_hist  = ws + 1245184;       // 1048576
  float* h_g     = ws + 2293760;       // 8192  (end 2301952 floats ~9.2MB)

  (void)in_sizes; (void)n_in; (void)out_size; (void)ws_size;

  k_prep<<<768, 256, 0, stream>>>(W_in, W_out, W_rec, W_adapt,
                                  W_inT, W_outT, W_recT, W_adaptT);
  k_embed<<<Bn * Tn, 256, 0, stream>>>(x, W_inT, b_in, emb);
  k_ltc<<<Bn, 512, 0, stream>>>(W_recT, W_adaptT, tau, emb, h_g, h_hist);
  k_out<<<Bn * Tn, 128, 0, stream>>>(h_hist, W_outT, b_out, outp);
}

// Round 22
// 5244.167 us; speedup vs baseline: 1.9137x; 1.9137x over previous
//
#include <hip/hip_runtime.h>
#include <math.h>

#pragma clang fp contract(off)

// LTC network: B=32, T=128, IN=128, H=256, OUT=128, 5 RK4 steps/t, dt=0.01
// Round 22: bit-exact arithmetic (absmax 0.0 since R9). Lever vs R13 (best,
// 5551us): SPLIT h-distribution across the two independent pipes measured
// so far — j=0..159 via readlane (VALU, ~7.4cy/op), j=160..255 via uniform
// b128 LDS broadcasts (DS pipe, ~10cy/instr). R13 is VALU-issue-bound
// (5200cy/stage), R16 DS-throughput-bound (6216cy/stage); running both
// concurrently balances at ~3500cy/stage. Values and ascending fmaf order
// unchanged -> bit-identical (both paths independently validated).
// Structure: 512 thr role-split (2 waves/SIMD), w[192] pinned (arch+AGPR),
// rows 192..255 in LDS bundles, partA exchange, 2 barriers/stage.
// Numerics (DO NOT TOUCH — bit-exact vs XLA-CPU golden):
//  dots: ascending-k __builtin_fmaf chain from 0.0; x/bias added after,
//  unfused; sigmoid = 1/(1+CephesExp(-z)) per GenerateVF32Exp; unfused RK4
//  elementwise; fp contract off file-wide.

#define Bn 32
#define Tn 128
#define INn 128
#define Hn 256
#define OUTn 128
#define NSTEPS 5

__device__ __forceinline__ float f32clip(float x, float lo, float hi) {
  float y = (x >= lo) ? x : lo;
  y = (y <= hi) ? y : hi;
  return (x == x) ? y : x;    // NaN propagates (safety; none occur)
}

// XLA CPU GenerateVF32Exp (Cephes expf), bit-exact reconstruction.
__device__ __forceinline__ float xla_expf(float x) {
  x = fminf(x, 88.3762626647950f);         // clamp high
  x = fmaxf(x, -88.3762626647949f);        // clamp low
  float fx = floorf(__builtin_fmaf(x, 1.44269504088896341f, 0.5f)); // fused
  float tmp = __fmul_rn(0.693359375f, fx);         // unfused Cody-Waite hi
  float z  = __fmul_rn(-2.12194440e-4f, fx);       // unfused Cody-Waite lo
  float r  = __fsub_rn(x, tmp);
  r = __fsub_rn(r, z);
  float r2 = __fmul_rn(r, r);
  float y = __builtin_fmaf(r, 1.9875691500e-4f, 1.3981999507e-3f);  // MulAdd
  y = __builtin_fmaf(y, r, 8.3334519073e-3f);
  y = __builtin_fmaf(y, r, 4.1665795894e-2f);
  y = __builtin_fmaf(y, r, 1.6666665459e-1f);
  y = __builtin_fmaf(y, r, 5.0000001201e-1f);
  y = __builtin_fmaf(y, r2, r);
  y = __fadd_rn(1.0f, y);
  int m = (int)fx;                          // FPToSI (fx integral)
  float s = __int_as_float((m + 127) << 23);
  return __fmul_rn(y, s);
}

// LogisticExpander: 1 / (1 + exp(-z))
__device__ __forceinline__ float xla_sigmoid(float zin) {
  float e = xla_expf(-zin);
  return 1.0f / __fadd_rn(1.0f, e);        // IEEE f32 div
}

__device__ __forceinline__ float rdlane(float v, int l) {
  return __int_as_float(__builtin_amdgcn_readlane(__float_as_int(v), l));
}

__global__ __launch_bounds__(256) void k_prep(const float* __restrict__ W_in,
                                              const float* __restrict__ W_out,
                                              const float* __restrict__ W_rec,
                                              const float* __restrict__ W_adapt,
                                              float* __restrict__ W_inT,
                                              float* __restrict__ W_outT,
                                              float* __restrict__ W_recT,
                                              float* __restrict__ W_adaptT) {
  int idx = blockIdx.x * 256 + threadIdx.x;     // 768*256 = 196608
  if (idx < 32768) {            // W_in [256][128] -> W_inT[j][h]
    int h = idx >> 7, j = idx & 127;
    W_inT[j * Hn + h] = W_in[idx];
  } else if (idx < 65536) {     // W_out [128][256] -> W_outT[i][o]
    int k = idx - 32768; int o = k >> 8, i = k & 255;
    W_outT[i * OUTn + o] = W_out[k];
  } else if (idx < 131072) {    // W_rec [256][256] -> W_recT[c][r]
    int k = idx - 65536; int r = k >> 8, c = k & 255;
    W_recT[c * Hn + r] = W_rec[k];
  } else {                      // W_adapt -> W_adaptT[c][r]
    int k = idx - 131072; int r = k >> 8, c = k & 255;
    W_adaptT[c * Hn + r] = W_adapt[k];
  }
}

// emb[b,t,h] = (ascending-i fmaf chain, Eigen) x[b,t,:].W_in[h,:], then + b_in
__global__ __launch_bounds__(256) void k_embed(const float* __restrict__ xin,
                                               const float* __restrict__ W_inT,
                                               const float* __restrict__ b_in,
                                               float* __restrict__ emb) {
  __shared__ float xs[INn];
  int bt = blockIdx.x, h = threadIdx.x;
  if (h < INn) xs[h] = xin[bt * INn + h];
  __syncthreads();
  float d = 0.f;
  #pragma unroll
  for (int j = 0; j < INn; ++j)
    d = __builtin_fmaf(xs[j], W_inT[j * Hn + h], d);  // Eigen gebp chain
  emb[bt * Hn + h] = __fadd_rn(d, b_in[h]);           // + b_in separate op
}

__global__ __launch_bounds__(512)
__attribute__((amdgpu_waves_per_eu(2, 2)))
void k_ltc(const float* __restrict__ W_recT,
           const float* __restrict__ W_adaptT,
           const float* __restrict__ tau,
           const float* __restrict__ emb,
           float* __restrict__ h_hist) {
  const int b = blockIdx.x;
  const int tid = threadIdx.x;
  const int role = tid >> 8;     // 0: S-chain (W_rec) + elementwise; 1: A-chain
  const int i = tid & 255;
  const int lane = tid & 63;

  __shared__ __align__(16) float h_lds[Hn];        // 1 KB
  __shared__ float partA[Hn];                      // 1 KB
  __shared__ __align__(16) float4 wlds[16][512];   // 128 KB: j=192..255 bundles

  const float* WT = role ? W_adaptT : W_recT;
  float w[192];
  #pragma unroll
  for (int m = 0; m < 192; ++m) w[m] = WT[m * Hn + i];   // coalesced one-time
  #pragma unroll
  for (int m = 0; m < 192; ++m) asm volatile("" : "+v"(w[m]));  // pin resident
  #pragma unroll
  for (int r4 = 0; r4 < 16; ++r4) {                // j = 192..255 into LDS
    float4 v;
    v.x = WT[(192 + 4*r4 + 0) * Hn + i];
    v.y = WT[(192 + 4*r4 + 1) * Hn + i];
    v.z = WT[(192 + 4*r4 + 2) * Hn + i];
    v.w = WT[(192 + 4*r4 + 3) * Hn + i];
    wlds[r4][tid] = v;
  }
  const float tau_i = tau[i];
  const float C_DT6 = (float)(0.01 / 6.0);  // f32(DT/6.0), weak-scalar cast
  float h = 0.f, hcur = 0.f, acc = 0.f;
  if (role == 0) h_lds[i] = 0.f;
  __syncthreads();

  #pragma unroll 1
  for (int t = 0; t < Tn; ++t) {
    const float x = (role == 0) ? emb[(b * Tn + t) * Hn + i] : 0.f;
    #pragma unroll 1
    for (int s = 0; s < NSTEPS; ++s) {
      #pragma unroll 1
      for (int st = 0; st < 4; ++st) {
        // pack state for the readlane portion (conflict-free b32 reads)
        const float vh0 = h_lds[lane];
        const float vh1 = h_lds[64 + lane];
        const float vh2 = h_lds[128 + lane];
        const float4* h4 = reinterpret_cast<const float4*>(h_lds);
        // dot: ascending-j fmaf chain from 0 (Eigen gebp per-element chain).
        // j=0..159: readlane (VALU pipe). j=160..255: b128 broadcast (DS).
        float d = 0.f;
        #pragma unroll
        for (int j = 0; j < 64; ++j)
          d = __builtin_fmaf(rdlane(vh0, j), w[j], d);
        #pragma unroll
        for (int j = 0; j < 64; ++j)
          d = __builtin_fmaf(rdlane(vh1, j), w[64 + j], d);
        #pragma unroll
        for (int j = 0; j < 32; ++j)
          d = __builtin_fmaf(rdlane(vh2, j), w[128 + j], d);
        #pragma unroll
        for (int j4 = 40; j4 < 48; ++j4) {           // j = 160..191, w resident
          const float4 hv = h4[j4];                  // uniform b128 broadcast
          d = __builtin_fmaf(hv.x, w[4*j4 + 0], d);
          d = __builtin_fmaf(hv.y, w[4*j4 + 1], d);
          d = __builtin_fmaf(hv.z, w[4*j4 + 2], d);
          d = __builtin_fmaf(hv.w, w[4*j4 + 3], d);
        }
        #pragma unroll
        for (int r4 = 0; r4 < 16; ++r4) {            // j = 192..255, w from LDS
          const float4 hv = h4[48 + r4];             // uniform b128 broadcast
          const float4 wb = wlds[r4][tid];
          d = __builtin_fmaf(hv.x, wb.x, d);
          d = __builtin_fmaf(hv.y, wb.y, d);
          d = __builtin_fmaf(hv.z, wb.z, d);
          d = __builtin_fmaf(hv.w, wb.w, d);
        }
        if (role == 1) partA[i] = d;
        __syncthreads();
        if (role == 0) {
          float S = __fadd_rn(x, d);              // S = x + h@W_rec.T
          float z = __fadd_rn(S, partA[i]);       // S + h@W_adapt.T
          float sig = xla_sigmoid(z);             // 1/(1+exp(-z)), Cephes exp
          float tvc = f32clip(__fmul_rn(tau_i, sig), 1e-6f, 1e6f);
          float kk = __fsub_rn(S, hcur) / tvc;    // separate sub, IEEE div
          if (st == 0) {
            acc = kk;
            hcur = __fadd_rn(h, __fmul_rn(0.005f, kk));
          } else if (st == 1) {
            acc = __fadd_rn(acc, __fmul_rn(2.f, kk));
            hcur = __fadd_rn(h, __fmul_rn(0.005f, kk));
          } else if (st == 2) {
            acc = __fadd_rn(acc, __fmul_rn(2.f, kk));
            hcur = __fadd_rn(h, __fmul_rn(0.01f, kk));
          } else {
            acc = __fadd_rn(acc, kk);
            float dl = f32clip(__fmul_rn(acc, C_DT6), -1e6f, 1e6f);
            h = __fadd_rn(h, dl);
            hcur = h;
          }
          h_lds[i] = hcur;
        }
        __syncthreads();
      }
    }
    if (role == 0) h_hist[(b * Tn + t) * Hn + i] = h;
  }
}

// out[b,t,o] = (ascending fmaf chain) h.W_out[o,:], then + b_out[o]
__global__ __launch_bounds__(128) void k_out(const float* __restrict__ h_hist,
                                             const float* __restrict__ W_outT,
                                             const float* __restrict__ b_out,
                                             float* __restrict__ outp) {
  __shared__ float hs[Hn];
  int bt = blockIdx.x, o = threadIdx.x;
  hs[o] = h_hist[bt * Hn + o];
  hs[o + 128] = h_hist[bt * Hn + o + 128];
  __syncthreads();
  float d = 0.f;
  #pragma unroll
  for (int j = 0; j < Hn; ++j)
    d = __builtin_fmaf(hs[j], W_outT[j * OUTn + o], d);
  outp[bt * OUTn + o] = __fadd_rn(d, b_out[o]);
}

extern "C" void kernel_launch(void* const* d_in, const int* in_sizes, int n_in,
                              void* d_out, int out_size, void* d_ws, size_t ws_size,
                              hipStream_t stream) {
  const float* x       = (const float*)d_in[0];
  const float* W_in    = (const float*)d_in[1];
  const float* b_in    = (const float*)d_in[2];
  const float* W_rec   = (const float*)d_in[3];
  const float* W_adapt = (const float*)d_in[4];
  const float* W_out   = (const float*)d_in[5];
  const float* b_out   = (const float*)d_in[6];
  const float* tau     = (const float*)d_in[7];
  float* outp = (float*)d_out;
  float* ws = (float*)d_ws;

  float* W_inT   = ws;                 // 32768
  float* W_outT  = ws + 32768;         // 32768
  float* W_recT  = ws + 65536;         // 65536
  float* W_adaptT= ws + 131072;        // 65536
  float* emb     = ws + 196608;        // 1048576
  float* h_hist  = ws + 1245184;       // 1048576  (end 2293760 floats ~9.2MB)

  (void)in_sizes; (void)n_in; (void)out_size; (void)ws_size;

  k_prep<<<768, 256, 0, stream>>>(W_in, W_out, W_rec, W_adapt,
                                  W_inT, W_outT, W_recT, W_adaptT);
  k_embed<<<Bn * Tn, 256, 0, stream>>>(x, W_inT, b_in, emb);
  k_ltc<<<Bn, 512, 0, stream>>>(W_recT, W_adaptT, tau, emb, h_hist);
  k_out<<<Bn * Tn, 128, 0, stream>>>(h_hist, W_outT, b_out, outp);
}